// Round 2
// baseline (538.978 us; speedup 1.0000x reference)
//
#include <hip/hip_runtime.h>
#include <stdint.h>

typedef __attribute__((ext_vector_type(8))) short short8;
typedef __attribute__((ext_vector_type(4))) float floatx4;

// Inputs are fp32, output fp32 (confirmed on-device R3: detect flag fired fp32;
// fp32 d_out write passed R4).

__device__ __forceinline__ float b2f(uint16_t u) {
  union { uint32_t i; float f; } v; v.i = ((uint32_t)u) << 16; return v.f;
}
__device__ __forceinline__ uint16_t f2b(float f) {
  union { float f; uint32_t i; } v; v.f = f;
  uint32_t r = v.i + 0x7FFFu + ((v.i >> 16) & 1u);
  return (uint16_t)(r >> 16);
}

// fp32 -> bf16, 8 elems/thread.
__global__ __launch_bounds__(256) void cvt_w(const float* __restrict__ src,
                                             uint16_t* __restrict__ dst, int n8) {
  const int idx = blockIdx.x * 256 + threadIdx.x;
  if (idx >= n8) return;
  const float4* s = (const float4*)src;
  float4 a = s[2 * idx], b = s[2 * idx + 1];
  uint16_t o[8] = {f2b(a.x), f2b(a.y), f2b(a.z), f2b(a.w),
                   f2b(b.x), f2b(b.y), f2b(b.z), f2b(b.w)};
  ((uint4*)dst)[idx] = *(const uint4*)o;
}

// All 6 small vectors in one launch (blockIdx = segment).
__global__ __launch_bounds__(256) void cvt_small6(
    const float* s0, uint16_t* d0, const float* s1, uint16_t* d1,
    const float* s2, uint16_t* d2, const float* s3, uint16_t* d3,
    const float* s4, uint16_t* d4, const float* s5, uint16_t* d5) {
  const float* srcs[6] = {s0, s1, s2, s3, s4, s5};
  uint16_t* dsts[6] = {d0, d1, d2, d3, d4, d5};
  const int lens[6] = {1536, 512, 1536, 512, 4096, 2048};
  const int b = blockIdx.x;
  const int n8 = lens[b] / 8;
  for (int i = threadIdx.x; i < n8; i += 256) {
    const float4* s = (const float4*)srcs[b];
    float4 a = s[2 * i], c = s[2 * i + 1];
    uint16_t o[8] = {f2b(a.x), f2b(a.y), f2b(a.z), f2b(a.w),
                     f2b(c.x), f2b(c.y), f2b(c.z), f2b(c.w)};
    ((uint4*)dsts[b])[i] = *(const uint4*)o;
  }
}

// Gather+convert the 16 heads' nope rows (first 128 of each 192) of wq_b
// into packed [2048,1536] bf16 weight + packed bias. fp32 source.
__global__ __launch_bounds__(192) void pack_wq(
    const float* __restrict__ w, const float* __restrict__ b,
    uint16_t* __restrict__ wp, uint16_t* __restrict__ bp) {
  const int row = blockIdx.x;                       // 0..2047
  const int src = (row >> 7) * 192 + (row & 127);   // head*192 + sub
  const int t = threadIdx.x;                        // 0..191
  const float4* s = (const float4*)w + (size_t)src * 384;
  float4 a = s[2 * t], c = s[2 * t + 1];
  uint16_t o[8] = {f2b(a.x), f2b(a.y), f2b(a.z), f2b(a.w),
                   f2b(c.x), f2b(c.y), f2b(c.z), f2b(c.w)};
  ((uint4*)(wp + (size_t)row * 1536))[t] = *(const uint4*)o;
  if (t == 0) bp[row] = f2b(b[src]);
}

// async global->LDS, 16B per lane (m97/m104). LDS dest must be
// wave-uniform-base + lane*16 (linear); global source may be per-lane.
__device__ __forceinline__ void async_copy16(const uint16_t* g, uint16_t* l) {
  __builtin_amdgcn_global_load_lds(
      (const __attribute__((address_space(1))) void*)g,
      (__attribute__((address_space(3))) void*)l,
      16, 0, 0);
}

// Stage a 256x64 bf16 tile (G points at tile origin: row 0, k0) into lbuf.
// LDS layout: [256][64] linear rows; the 8 16B chunks within each row hold
// global chunk (c ^ (row&7)) -> read side applies the same XOR (involution).
// Write side is linear (global_load_lds requirement); swizzle is done by
// permuting the per-lane GLOBAL source column (rule #21 / m201 pattern).
__device__ __forceinline__ void stage256(const uint16_t* __restrict__ G, int ldg,
                                         uint16_t* __restrict__ lbuf, int tid) {
  const int rr = tid >> 3;    // 0..63 rows per round
  const int ch = tid & 7;     // chunk slot within row
#pragma unroll
  for (int r = 0; r < 4; ++r) {
    const int row = r * 64 + rr;
    const int sc = (ch ^ (row & 7)) << 3;   // swizzled source column (elems)
    async_copy16(G + (size_t)row * ldg + sc, lbuf + (r << 12) + (tid << 3));
  }
}

// C[M,N] = A[M,K] @ W[N,K]^T + bias[N]; bf16 in, fp32 accum.
// 256x256 tile, BK=64, 8 waves (2Mx4N), per-wave 128x64 output.
// 4-phase barrier rhythm per K-tile (m196/m201 lever): each phase =
// {ds_read issue; s_barrier; lgkmcnt(0)+sched_barrier; setprio(1) 16xMFMA
// setprio(0); s_barrier}. Phase p's ds_reads overlap phase p-1's MFMA drain.
// Depth-2 K-tile prefetch with counted vmcnt (never 0 in steady state):
// stage tile kt+2 into buf c after the closing barrier (all reads of c done),
// then vmcnt(8)+barrier gates buf c^1 for the next iteration.
// Requires: M%256==0, N%256==0, K%64==0, K>=128, gridDim.x%8==0.
template <bool F32OUT>
__global__ __launch_bounds__(512, 2) void gemm256(
    const uint16_t* __restrict__ A, int lda,
    const uint16_t* __restrict__ W,
    const uint16_t* __restrict__ bias, void* __restrict__ Cout,
    int N, int K, int nbx)
{
  __shared__ uint16_t As[2][256 * 64];   // 64 KiB
  __shared__ uint16_t Bs[2][256 * 64];   // 64 KiB  (total 128 KiB)
  const int tid  = threadIdx.x;
  const int lane = tid & 63;
  const int wave = tid >> 6;
  const int wr = wave >> 2;      // 0..1  (M direction, 128 rows each)
  const int wc = wave & 3;       // 0..3  (N direction, 64 cols each)
  const int ml = lane & 15;
  const int quad = lane >> 4;

  // T1: bijective XCD swizzle (gridDim.x % 8 == 0) + row-major decomposition.
  const int nwg = gridDim.x;
  const int bid = blockIdx.x;
  const int swz = (bid & 7) * (nwg >> 3) + (bid >> 3);
  const int bx = swz % nbx;
  const int by = swz / nbx;
  const int bm = by * 256, bn = bx * 256;

  const int NT = K >> 6;
  const uint16_t* Ag = A + (size_t)bm * lda;
  const uint16_t* Wg = W + (size_t)bn * K;

  floatx4 acc[8][4];
#pragma unroll
  for (int i = 0; i < 8; ++i)
#pragma unroll
    for (int j = 0; j < 4; ++j)
      acc[i][j] = (floatx4){0.f, 0.f, 0.f, 0.f};

  // Prologue: stage K-tiles 0 and 1 (8 loads per wave per K-tile pair A+B),
  // then gate tile 0 (counted: tile 1's 8 loads stay in flight).
  stage256(Ag,      lda, As[0], tid);
  stage256(Wg,      K,   Bs[0], tid);
  stage256(Ag + 64, lda, As[1], tid);
  stage256(Wg + 64, K,   Bs[1], tid);
  asm volatile("s_waitcnt vmcnt(8)" ::: "memory");
  __builtin_amdgcn_s_barrier();
  __builtin_amdgcn_sched_barrier(0);

  for (int kt = 0; kt < NT; ++kt) {
    const int c = kt & 1;
    const uint16_t* Ab = As[c];
    const uint16_t* Bb = Bs[c];

    short8 bfr[4][2];
#pragma unroll
    for (int ph = 0; ph < 4; ++ph) {
      // --- ds_read issue for this phase ---
      if (ph == 0) {
        // All 4 B col-frags (8 reads), live across the 4 phases.
#pragma unroll
        for (int fc = 0; fc < 4; ++fc) {
          const int row = wc * 64 + fc * 16 + ml;
#pragma unroll
          for (int kk = 0; kk < 2; ++kk) {
            const int chunk = (kk * 4 + quad) ^ (row & 7);
            bfr[fc][kk] = *(const short8*)(Bb + row * 64 + chunk * 8);
          }
        }
      }
      short8 afr[2][2];
#pragma unroll
      for (int f = 0; f < 2; ++f) {
        const int row = wr * 128 + (ph * 2 + f) * 16 + ml;
#pragma unroll
        for (int kk = 0; kk < 2; ++kk) {
          const int chunk = (kk * 4 + quad) ^ (row & 7);
          afr[f][kk] = *(const short8*)(Ab + row * 64 + chunk * 8);
        }
      }
      // --- phase barrier: cluster all waves' MFMA together; this phase's
      // ds_reads were issued above and overlap the previous cluster's drain.
      __builtin_amdgcn_s_barrier();
      asm volatile("s_waitcnt lgkmcnt(0)" ::: "memory");
      __builtin_amdgcn_sched_barrier(0);   // rule #18: pin MFMA after lgkmcnt
      __builtin_amdgcn_s_setprio(1);
#pragma unroll
      for (int kk = 0; kk < 2; ++kk)       // kk-outer: 8 independent chains
#pragma unroll
        for (int f = 0; f < 2; ++f)
#pragma unroll
          for (int fc = 0; fc < 4; ++fc)
            acc[ph * 2 + f][fc] = __builtin_amdgcn_mfma_f32_16x16x32_bf16(
                afr[f][kk], bfr[fc][kk], acc[ph * 2 + f][fc], 0, 0, 0);
      __builtin_amdgcn_s_setprio(0);
      __builtin_amdgcn_s_barrier();        // end of phase
      __builtin_amdgcn_sched_barrier(0);
    }
    // After phase 3's closing barrier: all waves done reading buf c.
    // Issue depth-2 prefetch into buf c (overlaps phase-3 MFMA drain),
    // then gate buf c^1 (tile kt+1) with a counted drain.
    if (kt + 2 < NT) {
      stage256(Ag + (size_t)(kt + 2) * 64, lda, As[c], tid);
      stage256(Wg + (size_t)(kt + 2) * 64, K,   Bs[c], tid);
      asm volatile("s_waitcnt vmcnt(8)" ::: "memory");   // drain tile kt+1
      __builtin_amdgcn_s_barrier();
      __builtin_amdgcn_sched_barrier(0);
    } else if (kt + 1 < NT) {
      asm volatile("s_waitcnt vmcnt(0)" ::: "memory");   // last tile: full drain
      __builtin_amdgcn_s_barrier();
      __builtin_amdgcn_sched_barrier(0);
    }
  }

  // Epilogue. C/D layout: col = lane&15, row = quad*4 + reg (m89/m91).
#pragma unroll
  for (int fc = 0; fc < 4; ++fc) {
    const int col = bn + wc * 64 + fc * 16 + ml;
    const float bv = b2f(bias[col]);
#pragma unroll
    for (int fr = 0; fr < 8; ++fr) {
      const int row0 = bm + wr * 128 + fr * 16 + quad * 4;
      if constexpr (F32OUT) {
        float* C32 = (float*)Cout;
#pragma unroll
        for (int r = 0; r < 4; ++r)
          C32[(size_t)(row0 + r) * N + col] = acc[fr][fc][r] + bv;
      } else {
        uint16_t* C = (uint16_t*)Cout;
#pragma unroll
        for (int r = 0; r < 4; ++r)
          C[(size_t)(row0 + r) * N + col] = f2b(acc[fr][fc][r] + bv);
      }
    }
  }
}

// Dual RMSNorm over a fused [T, 2048] buffer: cols 0..1535 normalized with wq
// (L=1536), cols 1536..2047 with wkv (L=512). In place. One row per block.
__global__ __launch_bounds__(256) void rmsnorm_dual(uint16_t* __restrict__ x,
                                                    const uint16_t* __restrict__ wq,
                                                    const uint16_t* __restrict__ wkv)
{
  __shared__ float red[4];
  __shared__ float invs[2];
  const int t = threadIdx.x;
  const int lane = t & 63;
  const int wave = t >> 6;          // waves 0-2: q segment; wave 3: kv segment
  uint16_t* xr = x + (size_t)blockIdx.x * 2048;

  uint4 v = ((const uint4*)xr)[t];
  const uint16_t* u = (const uint16_t*)&v;
  float lv[8];
  float ss = 0.f;
#pragma unroll
  for (int i = 0; i < 8; ++i) { lv[i] = b2f(u[i]); ss += lv[i] * lv[i]; }
#pragma unroll
  for (int o = 32; o >= 1; o >>= 1) ss += __shfl_down(ss, o, 64);
  if (lane == 0) red[wave] = ss;
  __syncthreads();
  if (t == 0)
    invs[0] = rsqrtf((red[0] + red[1] + red[2]) * (1.f / 1536.f) + 1.1920929e-7f);
  if (t == 64)
    invs[1] = rsqrtf(red[3] * (1.f / 512.f) + 1.1920929e-7f);
  __syncthreads();

  const float inv = (t < 192) ? invs[0] : invs[1];
  const uint16_t* wsrc = (t < 192) ? (wq + t * 8) : (wkv + (t - 192) * 8);
  uint4 wv = *(const uint4*)wsrc;
  const uint16_t* wu = (const uint16_t*)&wv;
  uint16_t ob[8];
#pragma unroll
  for (int i = 0; i < 8; ++i) ob[i] = f2b(lv[i] * inv * b2f(wu[i]));
  ((uint4*)xr)[t] = *(const uint4*)ob;
}

// Per-token head-vs-head attention; RoPE drops out of softmax (k_pe broadcast
// over g => per-h additive constant). qn:[T,2048] kvb:[T,4096] out:[T,2048]
__global__ __launch_bounds__(256) void attn_kernel(
    const uint16_t* __restrict__ qn,
    const uint16_t* __restrict__ kvb,
    uint16_t* __restrict__ outp)
{
  __shared__ uint16_t q_s[2048];
  __shared__ uint16_t kv_s[16 * 264];
  __shared__ float s_at[256];
  const int t = blockIdx.x;
  const int tid = threadIdx.x;

  ((uint4*)q_s)[tid] = ((const uint4*)(qn + (size_t)t * 2048))[tid];
  {
    const uint4* src = (const uint4*)(kvb + (size_t)t * 4096);
#pragma unroll
    for (int r = 0; r < 2; ++r) {
      int c = tid + r * 256;
      ((uint4*)kv_s)[(c >> 5) * 33 + (c & 31)] = src[c];
    }
  }
  __syncthreads();

  const int h = tid >> 4, g = tid & 15;
  float sc = 0.f;
  const uint4* qh = (const uint4*)(q_s + h * 128);
  const uint4* kg = (const uint4*)(kv_s + g * 264);
#pragma unroll
  for (int c = 0; c < 16; ++c) {
    uint4 qa = qh[c], kb = kg[c];
    const uint16_t* qa_u = (const uint16_t*)&qa;
    const uint16_t* kb_u = (const uint16_t*)&kb;
#pragma unroll
    for (int i = 0; i < 8; ++i) sc += b2f(qa_u[i]) * b2f(kb_u[i]);
  }
  sc *= 0.07216878364870323f;   // (128+64)^-0.5
  float mx = sc;
#pragma unroll
  for (int o = 8; o >= 1; o >>= 1) mx = fmaxf(mx, __shfl_xor(mx, o, 16));
  const float e = __expf(sc - mx);
  float sum = e;
#pragma unroll
  for (int o = 8; o >= 1; o >>= 1) sum += __shfl_xor(sum, o, 16);
  s_at[tid] = e / sum;
  __syncthreads();

  float acc[8] = {0.f, 0.f, 0.f, 0.f, 0.f, 0.f, 0.f, 0.f};
  const int c8 = tid & 15;
#pragma unroll
  for (int gg = 0; gg < 16; ++gg) {
    const float a = s_at[h * 16 + gg];
    uint4 vv = *(const uint4*)(kv_s + gg * 264 + 128 + c8 * 8);
    const uint16_t* vu = (const uint16_t*)&vv;
#pragma unroll
    for (int i = 0; i < 8; ++i) acc[i] += a * b2f(vu[i]);
  }
  uint16_t ob[8];
#pragma unroll
  for (int i = 0; i < 8; ++i) ob[i] = f2b(acc[i]);
  *(uint4*)(outp + (size_t)t * 2048 + h * 128 + c8 * 8) = *(const uint4*)ob;
}

extern "C" void kernel_launch(void* const* d_in, const int* in_sizes, int n_in,
                              void* d_out, int out_size, void* d_ws, size_t ws_size,
                              hipStream_t stream)
{
  (void)in_sizes; (void)n_in; (void)out_size; (void)ws_size;
  const float* x_r       = (const float*)d_in[0];
  const float* wq_a_w_r  = (const float*)d_in[3];
  const float* wq_a_b_r  = (const float*)d_in[4];
  const float* q_norm_r  = (const float*)d_in[5];
  const float* wq_b_w_r  = (const float*)d_in[6];
  const float* wq_b_b_r  = (const float*)d_in[7];
  const float* wkv_a_w_r = (const float*)d_in[8];
  const float* wkv_a_b_r = (const float*)d_in[9];
  const float* kv_norm_r = (const float*)d_in[10];
  const float* wkv_b_w_r = (const float*)d_in[11];
  const float* wkv_b_b_r = (const float*)d_in[12];
  const float* wo_w_r    = (const float*)d_in[13];
  const float* wo_b_r    = (const float*)d_in[14];

  char* ws = (char*)d_ws;
  uint16_t* cx     = (uint16_t*)(ws);                 // 8192x2048 bf16 x; reused for attn out
  uint16_t* cwf    = (uint16_t*)(ws + 33554432);      // fused [wq_a(1536); wkv_a[0:512]] x2048
  uint16_t* wpack  = (uint16_t*)(ws + 41943040);      // 2048x1536
  uint16_t* cwkv_b = (uint16_t*)(ws + 48234496);      // 4096x512
  uint16_t* cwo    = (uint16_t*)(ws + 52428800);      // 2048x2048
  char*     smallb = ws + 60817408;
  uint16_t* bfused = (uint16_t*)(smallb);             // 2048 = bq_a(1536)||bkv_a(512)
  uint16_t* qnorm  = (uint16_t*)(smallb + 8192);      // 1536
  uint16_t* kvnorm = (uint16_t*)(smallb + 16384);     // 512
  uint16_t* bkv_b  = (uint16_t*)(smallb + 24576);     // 4096
  uint16_t* bwo    = (uint16_t*)(smallb + 40960);     // 2048
  uint16_t* bpack  = (uint16_t*)(smallb + 49152);     // 2048
  uint16_t* qakva  = (uint16_t*)(ws + 60882944);      // 8192x2048 (qa||kva per row)
  uint16_t* qn     = (uint16_t*)(ws + 94437376);      // 8192x2048
  uint16_t* kvb    = (uint16_t*)(ws + 127991808);     // 8192x4096  (end ~186 MiB)
  uint16_t* attn   = cx;                              // cx dead after fused GEMM1

  // conversions (fp32 -> bf16)
  cvt_w<<<8192, 256, 0, stream>>>(x_r,       cx,               2097152);
  cvt_w<<<1536, 256, 0, stream>>>(wq_a_w_r,  cwf,              393216);
  cvt_w<<<512,  256, 0, stream>>>(wkv_a_w_r, cwf + 1536*2048,  131072);  // first 512 rows only (k_pe dead)
  cvt_w<<<1024, 256, 0, stream>>>(wkv_b_w_r, cwkv_b,           262144);
  cvt_w<<<2048, 256, 0, stream>>>(wo_w_r,    cwo,              524288);
  cvt_small6<<<6, 256, 0, stream>>>(wq_a_b_r, bfused, wkv_a_b_r, bfused + 1536,
                                    q_norm_r, qnorm, kv_norm_r, kvnorm,
                                    wkv_b_b_r, bkv_b, wo_b_r, bwo);
  pack_wq<<<2048, 192, 0, stream>>>(wq_b_w_r, wq_b_b_r, wpack, bpack);

  // fused q_a + kv_a projection: [8192,2048] = x @ [wq_a; wkv_a[0:512]]^T
  gemm256<false><<<256, 512, 0, stream>>>(cx, 2048, cwf, bfused, qakva, 2048, 2048, 8);
  rmsnorm_dual<<<8192, 256, 0, stream>>>(qakva, qnorm, kvnorm);
  gemm256<false><<<256, 512, 0, stream>>>(qakva, 2048, wpack, bpack, qn, 2048, 1536, 8);
  gemm256<false><<<512, 512, 0, stream>>>(qakva + 1536, 2048, cwkv_b, bkv_b, kvb, 4096, 512, 16);
  attn_kernel<<<8192, 256, 0, stream>>>(qn, kvb, attn);
  gemm256<true><<<256, 512, 0, stream>>>(attn, 2048, cwo, bwo, d_out, 2048, 2048, 8);
}

// Round 3
// 512.402 us; speedup vs baseline: 1.0519x; 1.0519x over previous
//
#include <hip/hip_runtime.h>
#include <stdint.h>

typedef __attribute__((ext_vector_type(8))) short short8;
typedef __attribute__((ext_vector_type(4))) float floatx4;

// Inputs are fp32, output fp32 (confirmed on-device R3: detect flag fired fp32;
// fp32 d_out write passed R4).

__device__ __forceinline__ float b2f(uint16_t u) {
  union { uint32_t i; float f; } v; v.i = ((uint32_t)u) << 16; return v.f;
}
__device__ __forceinline__ uint16_t f2b(float f) {
  union { float f; uint32_t i; } v; v.f = f;
  uint32_t r = v.i + 0x7FFFu + ((v.i >> 16) & 1u);
  return (uint16_t)(r >> 16);
}

// fp32 -> bf16, 8 elems/thread.
__global__ __launch_bounds__(256) void cvt_w(const float* __restrict__ src,
                                             uint16_t* __restrict__ dst, int n8) {
  const int idx = blockIdx.x * 256 + threadIdx.x;
  if (idx >= n8) return;
  const float4* s = (const float4*)src;
  float4 a = s[2 * idx], b = s[2 * idx + 1];
  uint16_t o[8] = {f2b(a.x), f2b(a.y), f2b(a.z), f2b(a.w),
                   f2b(b.x), f2b(b.y), f2b(b.z), f2b(b.w)};
  ((uint4*)dst)[idx] = *(const uint4*)o;
}

// All 6 small vectors in one launch (blockIdx = segment).
__global__ __launch_bounds__(256) void cvt_small6(
    const float* s0, uint16_t* d0, const float* s1, uint16_t* d1,
    const float* s2, uint16_t* d2, const float* s3, uint16_t* d3,
    const float* s4, uint16_t* d4, const float* s5, uint16_t* d5) {
  const float* srcs[6] = {s0, s1, s2, s3, s4, s5};
  uint16_t* dsts[6] = {d0, d1, d2, d3, d4, d5};
  const int lens[6] = {1536, 512, 1536, 512, 4096, 2048};
  const int b = blockIdx.x;
  const int n8 = lens[b] / 8;
  for (int i = threadIdx.x; i < n8; i += 256) {
    const float4* s = (const float4*)srcs[b];
    float4 a = s[2 * i], c = s[2 * i + 1];
    uint16_t o[8] = {f2b(a.x), f2b(a.y), f2b(a.z), f2b(a.w),
                     f2b(c.x), f2b(c.y), f2b(c.z), f2b(c.w)};
    ((uint4*)dsts[b])[i] = *(const uint4*)o;
  }
}

// Gather+convert the 16 heads' nope rows (first 128 of each 192) of wq_b
// into packed [2048,1536] bf16 weight + packed bias. fp32 source.
__global__ __launch_bounds__(192) void pack_wq(
    const float* __restrict__ w, const float* __restrict__ b,
    uint16_t* __restrict__ wp, uint16_t* __restrict__ bp) {
  const int row = blockIdx.x;                       // 0..2047
  const int src = (row >> 7) * 192 + (row & 127);   // head*192 + sub
  const int t = threadIdx.x;                        // 0..191
  const float4* s = (const float4*)w + (size_t)src * 384;
  float4 a = s[2 * t], c = s[2 * t + 1];
  uint16_t o[8] = {f2b(a.x), f2b(a.y), f2b(a.z), f2b(a.w),
                   f2b(c.x), f2b(c.y), f2b(c.z), f2b(c.w)};
  ((uint4*)(wp + (size_t)row * 1536))[t] = *(const uint4*)o;
  if (t == 0) bp[row] = f2b(b[src]);
}

// async global->LDS, 16B per lane (m97/m104). LDS dest must be
// wave-uniform-base + lane*16 (linear); global source may be per-lane.
__device__ __forceinline__ void async_copy16(const uint16_t* g, uint16_t* l) {
  __builtin_amdgcn_global_load_lds(
      (const __attribute__((address_space(1))) void*)g,
      (__attribute__((address_space(3))) void*)l,
      16, 0, 0);
}

// Stage a 256x64 bf16 tile (G points at tile origin: row 0, k0) into lbuf.
// LDS layout: [256][64] linear rows; the 8 16B chunks within each row hold
// global chunk (c ^ (row&7)) -> read side applies the same XOR (involution).
// Write side is linear (global_load_lds requirement); swizzle is done by
// permuting the per-lane GLOBAL source column (rule #21 / m201 pattern).
__device__ __forceinline__ void stage256(const uint16_t* __restrict__ G, int ldg,
                                         uint16_t* __restrict__ lbuf, int tid) {
  const int rr = tid >> 3;    // 0..63 rows per round
  const int ch = tid & 7;     // chunk slot within row
#pragma unroll
  for (int r = 0; r < 4; ++r) {
    const int row = r * 64 + rr;
    const int sc = (ch ^ (row & 7)) << 3;   // swizzled source column (elems)
    async_copy16(G + (size_t)row * ldg + sc, lbuf + (r << 12) + (tid << 3));
  }
}

// C[M,N] = A[M,K] @ W[N,K]^T + bias[N]; bf16 in, fp32 accum.
// R1 structure (best measured: 87.4 us @ K=2048): 256x256 tile, BK=64,
// 8 waves (2Mx4N), 3 barriers/K-tile, counted vmcnt(8) gate (never 0 in
// steady state), XOR-swizzled LDS (0 bank conflicts), depth-2 prefetch.
// R3 delta: T5 setprio(1) around each 16-MFMA cluster (drift-window
// arbitration A/B). Requires: M%256==0, N%256==0, K%64==0, K>=128,
// sub-grid nwg%8==0.
template <bool F32OUT>
__device__ __forceinline__ void gemm256_body(
    const uint16_t* __restrict__ A, int lda,
    const uint16_t* __restrict__ W,
    const uint16_t* __restrict__ bias, void* __restrict__ Cout,
    int N, int K, int nbx, int bid, int nwg)
{
  __shared__ uint16_t As[2][256 * 64];   // 64 KiB
  __shared__ uint16_t Bs[2][256 * 64];   // 64 KiB  (total 128 KiB)
  const int tid  = threadIdx.x;
  const int lane = tid & 63;
  const int wave = tid >> 6;
  const int wr = wave >> 2;      // 0..1  (M direction, 128 rows each)
  const int wc = wave & 3;       // 0..3  (N direction, 64 cols each)
  const int ml = lane & 15;
  const int quad = lane >> 4;

  // T1: bijective XCD swizzle (nwg % 8 == 0) + row-major decomposition.
  const int swz = (bid & 7) * (nwg >> 3) + (bid >> 3);
  const int bx = swz % nbx;
  const int by = swz / nbx;
  const int bm = by * 256, bn = bx * 256;

  const int NT = K >> 6;
  const uint16_t* Ag = A + (size_t)bm * lda;
  const uint16_t* Wg = W + (size_t)bn * K;

  floatx4 acc[8][4];
#pragma unroll
  for (int i = 0; i < 8; ++i)
#pragma unroll
    for (int j = 0; j < 4; ++j)
      acc[i][j] = (floatx4){0.f, 0.f, 0.f, 0.f};

  // Prologue: stage K-tiles 0 and 1 (8 loads per wave per K-tile pair A+B).
  stage256(Ag,      lda, As[0], tid);
  stage256(Wg,      K,   Bs[0], tid);
  stage256(Ag + 64, lda, As[1], tid);
  stage256(Wg + 64, K,   Bs[1], tid);

  for (int kt = 0; kt < NT; ++kt) {
    const int c = kt & 1;
    // Counted drain: retire only this tile's 8 loads; the next tile's 8
    // (and any kt+2 already issued) stay in flight across the barrier.
    if (kt < NT - 1) { asm volatile("s_waitcnt vmcnt(8)" ::: "memory"); }
    else             { asm volatile("s_waitcnt vmcnt(0)" ::: "memory"); }
    __builtin_amdgcn_s_barrier();          // all waves' loads for buf c done
    __builtin_amdgcn_sched_barrier(0);

    const uint16_t* Ab = As[c];
    const uint16_t* Bb = Bs[c];

    // All B fragments for this K-tile (8 x ds_read_b128, swizzled chunks).
    short8 bfr[4][2];
#pragma unroll
    for (int fc = 0; fc < 4; ++fc) {
      const int row = wc * 64 + fc * 16 + ml;
#pragma unroll
      for (int kk = 0; kk < 2; ++kk) {
        const int chunk = (kk * 4 + quad) ^ (row & 7);
        bfr[fc][kk] = *(const short8*)(Bb + row * 64 + chunk * 8);
      }
    }

    // 4 phases: {4 A ds_reads; 16 MFMA}. No intra-tile barriers: waves
    // drift -> natural ds_read/MFMA overlap; setprio arbitrates (T5).
#pragma unroll
    for (int ph = 0; ph < 4; ++ph) {
      short8 afr[2][2];
#pragma unroll
      for (int f = 0; f < 2; ++f) {
        const int row = wr * 128 + (ph * 2 + f) * 16 + ml;
#pragma unroll
        for (int kk = 0; kk < 2; ++kk) {
          const int chunk = (kk * 4 + quad) ^ (row & 7);
          afr[f][kk] = *(const short8*)(Ab + row * 64 + chunk * 8);
        }
      }
      __builtin_amdgcn_s_setprio(1);
#pragma unroll
      for (int f = 0; f < 2; ++f)
#pragma unroll
        for (int fc = 0; fc < 4; ++fc)
#pragma unroll
          for (int kk = 0; kk < 2; ++kk)
            acc[ph * 2 + f][fc] = __builtin_amdgcn_mfma_f32_16x16x32_bf16(
                afr[f][kk], bfr[fc][kk], acc[ph * 2 + f][fc], 0, 0, 0);
      __builtin_amdgcn_s_setprio(0);
    }

    __builtin_amdgcn_s_barrier();          // all waves done READING buf c
    __builtin_amdgcn_sched_barrier(0);
    const int kn = kt + 2;                 // depth-2 prefetch into buf c
    if (kn < NT) {
      stage256(Ag + (size_t)kn * 64, lda, As[c], tid);
      stage256(Wg + (size_t)kn * 64, K,   Bs[c], tid);
    }
  }

  // Epilogue. C/D layout: col = lane&15, row = quad*4 + reg (m89/m91).
#pragma unroll
  for (int fc = 0; fc < 4; ++fc) {
    const int col = bn + wc * 64 + fc * 16 + ml;
    const float bv = b2f(bias[col]);
#pragma unroll
    for (int fr = 0; fr < 8; ++fr) {
      const int row0 = bm + wr * 128 + fr * 16 + quad * 4;
      if constexpr (F32OUT) {
        float* C32 = (float*)Cout;
#pragma unroll
        for (int r = 0; r < 4; ++r)
          C32[(size_t)(row0 + r) * N + col] = acc[fr][fc][r] + bv;
      } else {
        uint16_t* C = (uint16_t*)Cout;
#pragma unroll
        for (int r = 0; r < 4; ++r)
          C[(size_t)(row0 + r) * N + col] = f2b(acc[fr][fc][r] + bv);
      }
    }
  }
}

template <bool F32OUT>
__global__ __launch_bounds__(512, 2) void gemm256(
    const uint16_t* __restrict__ A, int lda,
    const uint16_t* __restrict__ W,
    const uint16_t* __restrict__ bias, void* __restrict__ Cout,
    int N, int K, int nbx)
{
  gemm256_body<F32OUT>(A, lda, W, bias, Cout, N, K, nbx,
                       (int)blockIdx.x, (int)gridDim.x);
}

// Merged GEMM2 (wq_b: [8192,2048] <- qakva[:, :1536] @ wpack^T) and
// GEMM3 (wkv_b: [8192,4096] <- qakva[:, 1536:] @ cwkv_b^T) in one launch.
// Blocks 0..255 -> GEMM2 (nwg 256); blocks 256..767 -> GEMM3 (nwg 512).
// Disjoint outputs; XCD mapping preserved (256 % 8 == 0).
__global__ __launch_bounds__(512, 2) void gemm23(
    const uint16_t* __restrict__ qakva,
    const uint16_t* __restrict__ wpack, const uint16_t* __restrict__ bpack,
    uint16_t* __restrict__ qn,
    const uint16_t* __restrict__ cwkv_b, const uint16_t* __restrict__ bkv_b,
    uint16_t* __restrict__ kvb)
{
  const int bid = (int)blockIdx.x;
  const bool g2 = bid < 256;
  const uint16_t* A    = g2 ? qakva : qakva + 1536;
  const uint16_t* W    = g2 ? wpack : cwkv_b;
  const uint16_t* bias = g2 ? bpack : bkv_b;
  uint16_t* C          = g2 ? qn    : kvb;
  const int N   = g2 ? 2048 : 4096;
  const int K   = g2 ? 1536 : 512;
  const int nbx = g2 ? 8    : 16;
  const int lb  = g2 ? bid  : bid - 256;
  const int nwg = g2 ? 256  : 512;
  gemm256_body<false>(A, 2048, W, bias, (void*)C, N, K, nbx, lb, nwg);
}

// Dual RMSNorm over a fused [T, 2048] buffer: cols 0..1535 normalized with wq
// (L=1536), cols 1536..2047 with wkv (L=512). In place. One row per block.
__global__ __launch_bounds__(256) void rmsnorm_dual(uint16_t* __restrict__ x,
                                                    const uint16_t* __restrict__ wq,
                                                    const uint16_t* __restrict__ wkv)
{
  __shared__ float red[4];
  __shared__ float invs[2];
  const int t = threadIdx.x;
  const int lane = t & 63;
  const int wave = t >> 6;          // waves 0-2: q segment; wave 3: kv segment
  uint16_t* xr = x + (size_t)blockIdx.x * 2048;

  uint4 v = ((const uint4*)xr)[t];
  const uint16_t* u = (const uint16_t*)&v;
  float lv[8];
  float ss = 0.f;
#pragma unroll
  for (int i = 0; i < 8; ++i) { lv[i] = b2f(u[i]); ss += lv[i] * lv[i]; }
#pragma unroll
  for (int o = 32; o >= 1; o >>= 1) ss += __shfl_down(ss, o, 64);
  if (lane == 0) red[wave] = ss;
  __syncthreads();
  if (t == 0)
    invs[0] = rsqrtf((red[0] + red[1] + red[2]) * (1.f / 1536.f) + 1.1920929e-7f);
  if (t == 64)
    invs[1] = rsqrtf(red[3] * (1.f / 512.f) + 1.1920929e-7f);
  __syncthreads();

  const float inv = (t < 192) ? invs[0] : invs[1];
  const uint16_t* wsrc = (t < 192) ? (wq + t * 8) : (wkv + (t - 192) * 8);
  uint4 wv = *(const uint4*)wsrc;
  const uint16_t* wu = (const uint16_t*)&wv;
  uint16_t ob[8];
#pragma unroll
  for (int i = 0; i < 8; ++i) ob[i] = f2b(lv[i] * inv * b2f(wu[i]));
  ((uint4*)xr)[t] = *(const uint4*)ob;
}

// Per-token head-vs-head attention; RoPE drops out of softmax (k_pe broadcast
// over g => per-h additive constant). qn:[T,2048] kvb:[T,4096] out:[T,2048]
__global__ __launch_bounds__(256) void attn_kernel(
    const uint16_t* __restrict__ qn,
    const uint16_t* __restrict__ kvb,
    uint16_t* __restrict__ outp)
{
  __shared__ uint16_t q_s[2048];
  __shared__ uint16_t kv_s[16 * 264];
  __shared__ float s_at[256];
  const int t = blockIdx.x;
  const int tid = threadIdx.x;

  ((uint4*)q_s)[tid] = ((const uint4*)(qn + (size_t)t * 2048))[tid];
  {
    const uint4* src = (const uint4*)(kvb + (size_t)t * 4096);
#pragma unroll
    for (int r = 0; r < 2; ++r) {
      int c = tid + r * 256;
      ((uint4*)kv_s)[(c >> 5) * 33 + (c & 31)] = src[c];
    }
  }
  __syncthreads();

  const int h = tid >> 4, g = tid & 15;
  float sc = 0.f;
  const uint4* qh = (const uint4*)(q_s + h * 128);
  const uint4* kg = (const uint4*)(kv_s + g * 264);
#pragma unroll
  for (int c = 0; c < 16; ++c) {
    uint4 qa = qh[c], kb = kg[c];
    const uint16_t* qa_u = (const uint16_t*)&qa;
    const uint16_t* kb_u = (const uint16_t*)&kb;
#pragma unroll
    for (int i = 0; i < 8; ++i) sc += b2f(qa_u[i]) * b2f(kb_u[i]);
  }
  sc *= 0.07216878364870323f;   // (128+64)^-0.5
  float mx = sc;
#pragma unroll
  for (int o = 8; o >= 1; o >>= 1) mx = fmaxf(mx, __shfl_xor(mx, o, 16));
  const float e = __expf(sc - mx);
  float sum = e;
#pragma unroll
  for (int o = 8; o >= 1; o >>= 1) sum += __shfl_xor(sum, o, 16);
  s_at[tid] = e / sum;
  __syncthreads();

  float acc[8] = {0.f, 0.f, 0.f, 0.f, 0.f, 0.f, 0.f, 0.f};
  const int c8 = tid & 15;
#pragma unroll
  for (int gg = 0; gg < 16; ++gg) {
    const float a = s_at[h * 16 + gg];
    uint4 vv = *(const uint4*)(kv_s + gg * 264 + 128 + c8 * 8);
    const uint16_t* vu = (const uint16_t*)&vv;
#pragma unroll
    for (int i = 0; i < 8; ++i) acc[i] += a * b2f(vu[i]);
  }
  uint16_t ob[8];
#pragma unroll
  for (int i = 0; i < 8; ++i) ob[i] = f2b(acc[i]);
  *(uint4*)(outp + (size_t)t * 2048 + h * 128 + c8 * 8) = *(const uint4*)ob;
}

extern "C" void kernel_launch(void* const* d_in, const int* in_sizes, int n_in,
                              void* d_out, int out_size, void* d_ws, size_t ws_size,
                              hipStream_t stream)
{
  (void)in_sizes; (void)n_in; (void)out_size; (void)ws_size;
  const float* x_r       = (const float*)d_in[0];
  const float* wq_a_w_r  = (const float*)d_in[3];
  const float* wq_a_b_r  = (const float*)d_in[4];
  const float* q_norm_r  = (const float*)d_in[5];
  const float* wq_b_w_r  = (const float*)d_in[6];
  const float* wq_b_b_r  = (const float*)d_in[7];
  const float* wkv_a_w_r = (const float*)d_in[8];
  const float* wkv_a_b_r = (const float*)d_in[9];
  const float* kv_norm_r = (const float*)d_in[10];
  const float* wkv_b_w_r = (const float*)d_in[11];
  const float* wkv_b_b_r = (const float*)d_in[12];
  const float* wo_w_r    = (const float*)d_in[13];
  const float* wo_b_r    = (const float*)d_in[14];

  char* ws = (char*)d_ws;
  uint16_t* cx     = (uint16_t*)(ws);                 // 8192x2048 bf16 x; reused for attn out
  uint16_t* cwf    = (uint16_t*)(ws + 33554432);      // fused [wq_a(1536); wkv_a[0:512]] x2048
  uint16_t* wpack  = (uint16_t*)(ws + 41943040);      // 2048x1536
  uint16_t* cwkv_b = (uint16_t*)(ws + 48234496);      // 4096x512
  uint16_t* cwo    = (uint16_t*)(ws + 52428800);      // 2048x2048
  char*     smallb = ws + 60817408;
  uint16_t* bfused = (uint16_t*)(smallb);             // 2048 = bq_a(1536)||bkv_a(512)
  uint16_t* qnorm  = (uint16_t*)(smallb + 8192);      // 1536
  uint16_t* kvnorm = (uint16_t*)(smallb + 16384);     // 512
  uint16_t* bkv_b  = (uint16_t*)(smallb + 24576);     // 4096
  uint16_t* bwo    = (uint16_t*)(smallb + 40960);     // 2048
  uint16_t* bpack  = (uint16_t*)(smallb + 49152);     // 2048
  uint16_t* qakva  = (uint16_t*)(ws + 60882944);      // 8192x2048 (qa||kva per row)
  uint16_t* qn     = (uint16_t*)(ws + 94437376);      // 8192x2048
  uint16_t* kvb    = (uint16_t*)(ws + 127991808);     // 8192x4096  (end ~186 MiB)
  uint16_t* attn   = cx;                              // cx dead after fused GEMM1

  // conversions (fp32 -> bf16)
  cvt_w<<<8192, 256, 0, stream>>>(x_r,       cx,               2097152);
  cvt_w<<<1536, 256, 0, stream>>>(wq_a_w_r,  cwf,              393216);
  cvt_w<<<512,  256, 0, stream>>>(wkv_a_w_r, cwf + 1536*2048,  131072);  // first 512 rows only (k_pe dead)
  cvt_w<<<1024, 256, 0, stream>>>(wkv_b_w_r, cwkv_b,           262144);
  cvt_w<<<2048, 256, 0, stream>>>(wo_w_r,    cwo,              524288);
  cvt_small6<<<6, 256, 0, stream>>>(wq_a_b_r, bfused, wkv_a_b_r, bfused + 1536,
                                    q_norm_r, qnorm, kv_norm_r, kvnorm,
                                    wkv_b_b_r, bkv_b, wo_b_r, bwo);
  pack_wq<<<2048, 192, 0, stream>>>(wq_b_w_r, wq_b_b_r, wpack, bpack);

  // fused q_a + kv_a projection: [8192,2048] = x @ [wq_a; wkv_a[0:512]]^T
  gemm256<false><<<256, 512, 0, stream>>>(cx, 2048, cwf, bfused, qakva, 2048, 2048, 8);
  rmsnorm_dual<<<8192, 256, 0, stream>>>(qakva, qnorm, kvnorm);
  gemm23<<<768, 512, 0, stream>>>(qakva, wpack, bpack, qn, cwkv_b, bkv_b, kvb);
  attn_kernel<<<8192, 256, 0, stream>>>(qn, kvb, attn);
  gemm256<true><<<256, 512, 0, stream>>>(attn, 2048, cwo, bwo, d_out, 2048, 2048, 8);
}